// Round 1
// baseline (1973.934 us; speedup 1.0000x reference)
//
#include <hip/hip_runtime.h>
#include <hip/hip_bf16.h>

#define NUM_E 64
#define KTOP 8
#define CAP 512
#define TT 2048
#define DD 2048
#define HH 1024

#define BM 128
#define BN 128
#define BK 32
#define LDSK 40  // padded LDS k-stride (bf16 elems): 80B rows -> ~2-way conflicts, 16B-aligned b128

typedef __attribute__((ext_vector_type(4))) float f4v;
typedef __attribute__((ext_vector_type(8))) short bf16x8;
typedef __attribute__((ext_vector_type(4))) short bf16x4;

static __device__ __forceinline__ short f2bf(float f) {
    __bf16 b = (__bf16)f;
    return __builtin_bit_cast(short, b);
}

// ---------------- init: zero out[] and counts[] ----------------
__global__ __launch_bounds__(256) void k_init(float* __restrict__ out, int* __restrict__ counts) {
    int idx = blockIdx.x * 256 + threadIdx.x;
    f4v z = {0.f, 0.f, 0.f, 0.f};
    f4v* o4 = (f4v*)out;
    for (int i = idx; i < (TT * DD) / 4; i += 1024 * 256) o4[i] = z;
    if (idx < NUM_E) counts[idx] = 0;
}

// ---------------- router: logits = x @ gate_w (f32) ----------------
// one wave handles 4 tokens; lane = expert
__global__ __launch_bounds__(256) void k_router(const float* __restrict__ x,
                                                const float* __restrict__ gw,
                                                float* __restrict__ logits) {
    int lane = threadIdx.x & 63, wid = threadIdx.x >> 6;
    int t0 = blockIdx.x * 16 + wid * 4;
    const float* x0 = x + (size_t)t0 * DD;
    float a0 = 0.f, a1 = 0.f, a2 = 0.f, a3 = 0.f;
#pragma unroll 4
    for (int d = 0; d < DD; ++d) {
        float g = gw[d * NUM_E + lane];
        a0 = fmaf(x0[d], g, a0);
        a1 = fmaf(x0[DD + d], g, a1);
        a2 = fmaf(x0[2 * DD + d], g, a2);
        a3 = fmaf(x0[3 * DD + d], g, a3);
    }
    logits[(size_t)(t0 + 0) * NUM_E + lane] = a0;
    logits[(size_t)(t0 + 1) * NUM_E + lane] = a1;
    logits[(size_t)(t0 + 2) * NUM_E + lane] = a2;
    logits[(size_t)(t0 + 3) * NUM_E + lane] = a3;
}

// ---------------- topk + dispatch ----------------
// one wave per token; lane = expert. softmax, then 8x argmax with index tie-break.
__global__ __launch_bounds__(256) void k_topk(const float* __restrict__ logits,
                                              int* __restrict__ counts,
                                              int* __restrict__ slot_token,
                                              float* __restrict__ slot_wt) {
    int lane = threadIdx.x & 63, wid = threadIdx.x >> 6;
    int t = blockIdx.x * 4 + wid;
    float l = logits[(size_t)t * NUM_E + lane];
    float m = l;
#pragma unroll
    for (int off = 32; off; off >>= 1) m = fmaxf(m, __shfl_xor(m, off));
    float ex = __expf(l - m);
    float s = ex;
#pragma unroll
    for (int off = 32; off; off >>= 1) s += __shfl_xor(s, off);
    float p = ex / s;
#pragma unroll
    for (int k = 0; k < KTOP; ++k) {
        float v = p;
        int i = lane;
#pragma unroll
        for (int off = 32; off; off >>= 1) {
            float v2 = __shfl_xor(v, off);
            int i2 = __shfl_xor(i, off);
            if (v2 > v || (v2 == v && i2 < i)) { v = v2; i = i2; }
        }
        if (lane == i) {
            int pos = atomicAdd(&counts[i], 1);
            if (pos < CAP) {
                int slot = i * CAP + pos;
                slot_token[slot] = t;
                slot_wt[slot] = v;
            }
            p = -1.0f;
        }
    }
}

// ---------------- gate+up fused GEMM + SwiGLU -> h (bf16, pre-scaled by gate weight) ----
// tile 128x128, BK=32, 4 waves (2x2), 16x16x32 bf16 MFMA.
// LDS tiles stored [out-dim row][k] with stride LDSK; fragments read as two b64 at
// k-offsets 4*g and 16+4*g (g=lane>>4). Same permutation on A and B => exact dot.
__global__ __launch_bounds__(256) void k_gateup(
    const float* __restrict__ x, const float* __restrict__ wg, const float* __restrict__ wu,
    const int* __restrict__ counts, const int* __restrict__ slot_token,
    const float* __restrict__ slot_wt, ushort* __restrict__ hbuf) {
    const int e = blockIdx.z;
    int count = counts[e];
    if (count > CAP) count = CAP;
    const int mrow0 = blockIdx.y * BM;
    if (mrow0 >= count) return;
    const int ncol0 = blockIdx.x * BN;
    const int tid = threadIdx.x;
    const int lane = tid & 63, wid = tid >> 6;
    const int wm = wid >> 1, wn = wid & 1;
    const int lrow = lane & 15, g4 = lane >> 4;

    __shared__ ushort As[BM * LDSK];
    __shared__ ushort Bgs[BN * LDSK];
    __shared__ ushort Bus[BN * LDSK];

    // A staging: 4 units/thread: row = i*32 + (tid>>3), 4 k's at ac4*4
    const int ac4 = tid & 7;
    const float* aptr[4];
    int arow_l[4];
#pragma unroll
    for (int i = 0; i < 4; ++i) {
        int r = i * 32 + (tid >> 3);
        arow_l[i] = r;
        int rg = mrow0 + r;
        if (rg < count) {
            int tok = slot_token[e * CAP + rg];
            aptr[i] = x + (size_t)tok * DD + ac4 * 4;
        } else {
            aptr[i] = nullptr;
        }
    }

    // B staging: threads 0-127 -> Wg, 128-255 -> Wu. unit: 4 h-cols x 8 k-rows.
    const int bu_idx = tid & 127;
    const int h0 = (bu_idx & 31) * 4;
    const int k0 = (bu_idx >> 5) * 8;
    const float* bptr = ((tid < 128) ? wg : wu) + ((size_t)e * DD + k0) * HH + ncol0 + h0;
    ushort* bLds = (tid < 128) ? Bgs : Bus;

    const f4v fz = {0.f, 0.f, 0.f, 0.f};
    f4v accg[4][4], accu[4][4];
#pragma unroll
    for (int m = 0; m < 4; ++m)
#pragma unroll
        for (int n = 0; n < 4; ++n) { accg[m][n] = fz; accu[m][n] = fz; }

    for (int kt = 0; kt < DD / BK; ++kt) {
        // stage A (f32 -> bf16, k-contiguous)
#pragma unroll
        for (int i = 0; i < 4; ++i) {
            f4v v = fz;
            if (aptr[i]) v = *(const f4v*)(aptr[i] + kt * BK);
            bf16x4 pk = {f2bf(v[0]), f2bf(v[1]), f2bf(v[2]), f2bf(v[3])};
            *(bf16x4*)&As[arow_l[i] * LDSK + ac4 * 4] = pk;
        }
        // stage B: 8 coalesced f32x4 loads (along h), 4x8 register transpose -> k-contiguous
        f4v bv[8];
#pragma unroll
        for (int j = 0; j < 8; ++j) bv[j] = *(const f4v*)(bptr + (size_t)j * HH);
#pragma unroll
        for (int i = 0; i < 4; ++i) {
            bf16x8 col = {f2bf(bv[0][i]), f2bf(bv[1][i]), f2bf(bv[2][i]), f2bf(bv[3][i]),
                          f2bf(bv[4][i]), f2bf(bv[5][i]), f2bf(bv[6][i]), f2bf(bv[7][i])};
            *(bf16x8*)&bLds[(h0 + i) * LDSK + k0] = col;
        }
        bptr += (size_t)BK * HH;
        __syncthreads();

        bf16x8 af[4];
#pragma unroll
        for (int m = 0; m < 4; ++m) {
            const ushort* pa = &As[(wm * 64 + m * 16 + lrow) * LDSK + g4 * 4];
            union { bf16x8 v8; bf16x4 v4[2]; } u;
            u.v4[0] = *(const bf16x4*)pa;
            u.v4[1] = *(const bf16x4*)(pa + 16);
            af[m] = u.v8;
        }
#pragma unroll
        for (int n = 0; n < 4; ++n) {
            const int c = (wn * 64 + n * 16 + lrow) * LDSK + g4 * 4;
            union { bf16x8 v8; bf16x4 v4[2]; } ug, uu;
            ug.v4[0] = *(const bf16x4*)&Bgs[c];
            ug.v4[1] = *(const bf16x4*)&Bgs[c + 16];
            uu.v4[0] = *(const bf16x4*)&Bus[c];
            uu.v4[1] = *(const bf16x4*)&Bus[c + 16];
#pragma unroll
            for (int m = 0; m < 4; ++m) {
                accg[m][n] = __builtin_amdgcn_mfma_f32_16x16x32_bf16(af[m], ug.v8, accg[m][n], 0, 0, 0);
                accu[m][n] = __builtin_amdgcn_mfma_f32_16x16x32_bf16(af[m], uu.v8, accu[m][n], 0, 0, 0);
            }
        }
        __syncthreads();
    }

    // epilogue: h = silu(g)*u * gateweight, bf16
#pragma unroll
    for (int m = 0; m < 4; ++m) {
#pragma unroll
        for (int r = 0; r < 4; ++r) {
            int row = mrow0 + wm * 64 + m * 16 + g4 * 4 + r;
            if (row < count) {
                float wgt = slot_wt[e * CAP + row];
                size_t base = (size_t)(e * CAP + row) * HH + ncol0 + wn * 64;
#pragma unroll
                for (int n = 0; n < 4; ++n) {
                    float g = accg[m][n][r], uv = accu[m][n][r];
                    float hv = (g / (1.f + __expf(-g))) * uv * wgt;
                    hbuf[base + n * 16 + lrow] = (ushort)f2bf(hv);
                }
            }
        }
    }
}

// ---------------- down GEMM + scatter-add into out ----------------
__global__ __launch_bounds__(256) void k_down(
    const ushort* __restrict__ hbuf, const float* __restrict__ wd,
    const int* __restrict__ counts, const int* __restrict__ slot_token,
    float* __restrict__ out) {
    const int e = blockIdx.z;
    int count = counts[e];
    if (count > CAP) count = CAP;
    const int mrow0 = blockIdx.y * BM;
    if (mrow0 >= count) return;
    const int ncol0 = blockIdx.x * BN;
    const int tid = threadIdx.x;
    const int lane = tid & 63, wid = tid >> 6;
    const int wm = wid >> 1, wn = wid & 1;
    const int lrow = lane & 15, g4 = lane >> 4;

    __shared__ ushort As[BM * LDSK];
    __shared__ ushort Bs[BN * LDSK];

    // A staging (h already bf16): 2 units/thread: row = i*64 + (tid>>2), 8 k's at k0a
    const int k0a = (tid & 3) * 8;
    bool aval[2];
    const ushort* haptr[2];
    int arow_l[2];
#pragma unroll
    for (int i = 0; i < 2; ++i) {
        int r = i * 64 + (tid >> 2);
        arow_l[i] = r;
        int rg = mrow0 + r;
        aval[i] = rg < count;
        haptr[i] = hbuf + (size_t)(e * CAP + (rg < CAP ? rg : 0)) * HH + k0a;
    }
    // B staging: unit: 4 d-cols x 4 k-rows
    const int d0 = (tid & 31) * 4;
    const int k0b = (tid >> 5) * 4;
    const float* bptr = wd + ((size_t)e * HH + k0b) * DD + ncol0 + d0;

    const f4v fz = {0.f, 0.f, 0.f, 0.f};
    f4v acc[4][4];
#pragma unroll
    for (int m = 0; m < 4; ++m)
#pragma unroll
        for (int n = 0; n < 4; ++n) acc[m][n] = fz;

    for (int kt = 0; kt < HH / BK; ++kt) {
#pragma unroll
        for (int i = 0; i < 2; ++i) {
            bf16x8 v = {0, 0, 0, 0, 0, 0, 0, 0};
            if (aval[i]) v = *(const bf16x8*)(haptr[i] + kt * BK);
            *(bf16x8*)&As[arow_l[i] * LDSK + k0a] = v;
        }
        f4v wv[4];
#pragma unroll
        for (int j = 0; j < 4; ++j) wv[j] = *(const f4v*)(bptr + (size_t)j * DD);
#pragma unroll
        for (int i = 0; i < 4; ++i) {
            bf16x4 col = {f2bf(wv[0][i]), f2bf(wv[1][i]), f2bf(wv[2][i]), f2bf(wv[3][i])};
            *(bf16x4*)&Bs[(d0 + i) * LDSK + k0b] = col;
        }
        bptr += (size_t)BK * DD;
        __syncthreads();

        bf16x8 af[4];
#pragma unroll
        for (int m = 0; m < 4; ++m) {
            const ushort* pa = &As[(wm * 64 + m * 16 + lrow) * LDSK + g4 * 4];
            union { bf16x8 v8; bf16x4 v4[2]; } u;
            u.v4[0] = *(const bf16x4*)pa;
            u.v4[1] = *(const bf16x4*)(pa + 16);
            af[m] = u.v8;
        }
#pragma unroll
        for (int n = 0; n < 4; ++n) {
            const int c = (wn * 64 + n * 16 + lrow) * LDSK + g4 * 4;
            union { bf16x8 v8; bf16x4 v4[2]; } ub;
            ub.v4[0] = *(const bf16x4*)&Bs[c];
            ub.v4[1] = *(const bf16x4*)&Bs[c + 16];
#pragma unroll
            for (int m = 0; m < 4; ++m)
                acc[m][n] = __builtin_amdgcn_mfma_f32_16x16x32_bf16(af[m], ub.v8, acc[m][n], 0, 0, 0);
        }
        __syncthreads();
    }

#pragma unroll
    for (int m = 0; m < 4; ++m) {
#pragma unroll
        for (int r = 0; r < 4; ++r) {
            int row = mrow0 + wm * 64 + m * 16 + g4 * 4 + r;
            if (row < count) {
                int tok = slot_token[e * CAP + row];
                float* obase = out + (size_t)tok * DD + ncol0 + wn * 64;
#pragma unroll
                for (int n = 0; n < 4; ++n) atomicAdd(obase + n * 16 + lrow, acc[m][n][r]);
            }
        }
    }
}

extern "C" void kernel_launch(void* const* d_in, const int* in_sizes, int n_in,
                              void* d_out, int out_size, void* d_ws, size_t ws_size,
                              hipStream_t stream) {
    const float* x = (const float*)d_in[0];       // [1,2048,2048]
    const float* gw = (const float*)d_in[1];      // [2048,64]
    const float* wg = (const float*)d_in[2];      // [64,2048,1024]
    const float* wu = (const float*)d_in[3];      // [64,2048,1024]
    const float* wd = (const float*)d_in[4];      // [64,1024,2048]
    float* out = (float*)d_out;                   // [T*D] then logits [T*E]
    float* logits = out + (size_t)TT * DD;

    char* ws = (char*)d_ws;
    int* counts = (int*)ws;                                      // 256 B
    int* slot_token = (int*)(ws + 1024);                         // 128 KB
    float* slot_wt = (float*)(ws + 1024 + NUM_E * CAP * 4);      // 128 KB
    ushort* hbuf = (ushort*)(ws + 1024 + 2 * NUM_E * CAP * 4);   // 64 MB bf16 [E*CAP][H]

    k_init<<<1024, 256, 0, stream>>>(out, counts);
    k_router<<<TT / 16, 256, 0, stream>>>(x, gw, logits);
    k_topk<<<TT / 4, 256, 0, stream>>>(logits, counts, slot_token, slot_wt);
    k_gateup<<<dim3(HH / BN, CAP / BM, NUM_E), 256, 0, stream>>>(x, wg, wu, counts, slot_token, slot_wt, hbuf);
    k_down<<<dim3(DD / BN, CAP / BM, NUM_E), 256, 0, stream>>>(hbuf, wd, counts, slot_token, out);
}

// Round 2
// 1004.853 us; speedup vs baseline: 1.9644x; 1.9644x over previous
//
#include <hip/hip_runtime.h>
#include <hip/hip_bf16.h>

#define NUM_E 64
#define KTOP 8
#define CAP 512
#define TT 2048
#define DD 2048
#define HH 1024

#define BK 32
#define LDSK 40  // padded LDS k-stride (bf16 elems): 80B rows, 16B-aligned for b128/b64

typedef __attribute__((ext_vector_type(4))) float f4v;
typedef __attribute__((ext_vector_type(8))) short bf16x8;
typedef __attribute__((ext_vector_type(4))) short bf16x4;

static __device__ __forceinline__ short f2bf(float f) {
    __bf16 b = (__bf16)f;
    return __builtin_bit_cast(short, b);
}

// ---------------- init: zero out[] and counts[] ----------------
__global__ __launch_bounds__(256) void k_init(float* __restrict__ out, int* __restrict__ counts) {
    int idx = blockIdx.x * 256 + threadIdx.x;
    f4v z = {0.f, 0.f, 0.f, 0.f};
    f4v* o4 = (f4v*)out;
    for (int i = idx; i < (TT * DD) / 4; i += 1024 * 256) o4[i] = z;
    if (idx < NUM_E) counts[idx] = 0;
}

// ---------------- router: logits = x @ gate_w (f32) ----------------
__global__ __launch_bounds__(256) void k_router(const float* __restrict__ x,
                                                const float* __restrict__ gw,
                                                float* __restrict__ logits) {
    int lane = threadIdx.x & 63, wid = threadIdx.x >> 6;
    int t0 = blockIdx.x * 16 + wid * 4;
    const float* x0 = x + (size_t)t0 * DD;
    float a0 = 0.f, a1 = 0.f, a2 = 0.f, a3 = 0.f;
#pragma unroll 4
    for (int d = 0; d < DD; ++d) {
        float g = gw[d * NUM_E + lane];
        a0 = fmaf(x0[d], g, a0);
        a1 = fmaf(x0[DD + d], g, a1);
        a2 = fmaf(x0[2 * DD + d], g, a2);
        a3 = fmaf(x0[3 * DD + d], g, a3);
    }
    logits[(size_t)(t0 + 0) * NUM_E + lane] = a0;
    logits[(size_t)(t0 + 1) * NUM_E + lane] = a1;
    logits[(size_t)(t0 + 2) * NUM_E + lane] = a2;
    logits[(size_t)(t0 + 3) * NUM_E + lane] = a3;
}

// ---------------- topk + dispatch ----------------
__global__ __launch_bounds__(256) void k_topk(const float* __restrict__ logits,
                                              int* __restrict__ counts,
                                              int* __restrict__ slot_token,
                                              float* __restrict__ slot_wt) {
    int lane = threadIdx.x & 63, wid = threadIdx.x >> 6;
    int t = blockIdx.x * 4 + wid;
    float l = logits[(size_t)t * NUM_E + lane];
    float m = l;
#pragma unroll
    for (int off = 32; off; off >>= 1) m = fmaxf(m, __shfl_xor(m, off));
    float ex = __expf(l - m);
    float s = ex;
#pragma unroll
    for (int off = 32; off; off >>= 1) s += __shfl_xor(s, off);
    float p = ex / s;
#pragma unroll
    for (int k = 0; k < KTOP; ++k) {
        float v = p;
        int i = lane;
#pragma unroll
        for (int off = 32; off; off >>= 1) {
            float v2 = __shfl_xor(v, off);
            int i2 = __shfl_xor(i, off);
            if (v2 > v || (v2 == v && i2 < i)) { v = v2; i = i2; }
        }
        if (lane == i) {
            int pos = atomicAdd(&counts[i], 1);
            if (pos < CAP) {
                int slot = i * CAP + pos;
                slot_token[slot] = t;
                slot_wt[slot] = v;
            }
            p = -1.0f;
        }
    }
}

// ---------------- gate+up fused GEMM + SwiGLU -> h ----------------
// Block tile 128 rows x 64 h-cols. 4 waves: wave (wm=wid>>1, wn=wid&1) owns a
// 64x32 sub-tile and accumulates BOTH gate and up (16 f4v = 64 AGPR).
// T14 register prefetch: loads for tile k+1 issued while MFMA of tile k runs.
__global__ __launch_bounds__(256, 2) void k_gateup(
    const float* __restrict__ x, const float* __restrict__ wg, const float* __restrict__ wu,
    const int* __restrict__ counts, const int* __restrict__ slot_token,
    const float* __restrict__ slot_wt, ushort* __restrict__ hbuf) {
    const int e = blockIdx.z;
    int count = counts[e];
    if (count > CAP) count = CAP;
    const int mrow0 = blockIdx.y * 128;
    if (mrow0 >= count) return;
    const int ncol0 = blockIdx.x * 64;
    const int tid = threadIdx.x;
    const int lane = tid & 63, wid = tid >> 6;
    const int wm = wid >> 1, wn = wid & 1;
    const int lrow = lane & 15, g4 = lane >> 4;

    __shared__ ushort As[128 * LDSK];
    __shared__ ushort Bgs[64 * LDSK];
    __shared__ ushort Bus[64 * LDSK];

    // A staging: 4 units/thread: row = i*32 + (tid>>3), 4 k's at ak
    const int ak = (tid & 7) * 4;
    const float* aptr[4];
    int arow[4];
#pragma unroll
    for (int i = 0; i < 4; ++i) {
        int r = i * 32 + (tid >> 3);
        arow[i] = r;
        int rg = mrow0 + r;
        if (rg < count) {
            int tok = slot_token[e * CAP + rg];
            aptr[i] = x + (size_t)tok * DD + ak;
        } else {
            aptr[i] = nullptr;
        }
    }

    // B staging: threads 0-127 -> Wg, 128-255 -> Wu. unit: 4 h-cols x 4 k-rows.
    const int bu_idx = tid & 127;
    const int bh = (bu_idx & 15) * 4;
    const int bk = (bu_idx >> 4) * 4;
    const float* bptr = ((tid < 128) ? wg : wu) + ((size_t)e * DD + bk) * HH + ncol0 + bh;
    ushort* bl = (tid < 128) ? Bgs : Bus;

    const f4v fz = {0.f, 0.f, 0.f, 0.f};
    f4v areg[4], breg[4];
#pragma unroll
    for (int i = 0; i < 4; ++i) { areg[i] = fz; breg[i] = fz; }
    // prologue: load tile 0
#pragma unroll
    for (int i = 0; i < 4; ++i)
        if (aptr[i]) areg[i] = *(const f4v*)(aptr[i]);
#pragma unroll
    for (int j = 0; j < 4; ++j) breg[j] = *(const f4v*)(bptr + (size_t)j * HH);

    f4v accg[4][2], accu[4][2];
#pragma unroll
    for (int m = 0; m < 4; ++m)
#pragma unroll
        for (int n = 0; n < 2; ++n) { accg[m][n] = fz; accu[m][n] = fz; }

    for (int kt = 0; kt < DD / BK; ++kt) {
        // write staged tile kt to LDS (cvt f32->bf16)
#pragma unroll
        for (int i = 0; i < 4; ++i) {
            bf16x4 pk = {f2bf(areg[i][0]), f2bf(areg[i][1]), f2bf(areg[i][2]), f2bf(areg[i][3])};
            *(bf16x4*)&As[arow[i] * LDSK + ak] = pk;
        }
#pragma unroll
        for (int i = 0; i < 4; ++i) {
            bf16x4 col = {f2bf(breg[0][i]), f2bf(breg[1][i]), f2bf(breg[2][i]), f2bf(breg[3][i])};
            *(bf16x4*)&bl[(bh + i) * LDSK + bk] = col;
        }
        __syncthreads();
        // prefetch tile kt+1 into regs (completes under the MFMAs below)
        if (kt < DD / BK - 1) {
            const int ko = (kt + 1) * BK;
#pragma unroll
            for (int i = 0; i < 4; ++i)
                if (aptr[i]) areg[i] = *(const f4v*)(aptr[i] + ko);
#pragma unroll
            for (int j = 0; j < 4; ++j)
                breg[j] = *(const f4v*)(bptr + ((size_t)ko + j) * HH);
        }
        // fragments + MFMA
        bf16x8 af[4];
#pragma unroll
        for (int m = 0; m < 4; ++m) {
            const ushort* pa = &As[(wm * 64 + m * 16 + lrow) * LDSK + g4 * 4];
            union { bf16x8 v8; bf16x4 v4[2]; } u;
            u.v4[0] = *(const bf16x4*)pa;
            u.v4[1] = *(const bf16x4*)(pa + 16);
            af[m] = u.v8;
        }
#pragma unroll
        for (int n = 0; n < 2; ++n) {
            const int c = (wn * 32 + n * 16 + lrow) * LDSK + g4 * 4;
            union { bf16x8 v8; bf16x4 v4[2]; } ug, uu;
            ug.v4[0] = *(const bf16x4*)&Bgs[c];
            ug.v4[1] = *(const bf16x4*)&Bgs[c + 16];
            uu.v4[0] = *(const bf16x4*)&Bus[c];
            uu.v4[1] = *(const bf16x4*)&Bus[c + 16];
#pragma unroll
            for (int m = 0; m < 4; ++m) {
                accg[m][n] = __builtin_amdgcn_mfma_f32_16x16x32_bf16(af[m], ug.v8, accg[m][n], 0, 0, 0);
                accu[m][n] = __builtin_amdgcn_mfma_f32_16x16x32_bf16(af[m], uu.v8, accu[m][n], 0, 0, 0);
            }
        }
        __syncthreads();
    }

    // epilogue: h = silu(g)*u * gate-weight, bf16
#pragma unroll
    for (int m = 0; m < 4; ++m) {
#pragma unroll
        for (int r = 0; r < 4; ++r) {
            int row = mrow0 + wm * 64 + m * 16 + g4 * 4 + r;
            if (row < count) {
                float wgt = slot_wt[e * CAP + row];
                size_t base = (size_t)(e * CAP + row) * HH + ncol0 + wn * 32;
#pragma unroll
                for (int n = 0; n < 2; ++n) {
                    float g = accg[m][n][r], uv = accu[m][n][r];
                    float hv = (g / (1.f + __expf(-g))) * uv * wgt;
                    hbuf[base + n * 16 + lrow] = (ushort)f2bf(hv);
                }
            }
        }
    }
}

// ---------------- down GEMM + scatter-add into out ----------------
// Block tile 128x128, 4 waves 2x2, wave 64x64 (16 f4v acc). T14 prefetch.
__global__ __launch_bounds__(256, 2) void k_down(
    const ushort* __restrict__ hbuf, const float* __restrict__ wd,
    const int* __restrict__ counts, const int* __restrict__ slot_token,
    float* __restrict__ out) {
    const int e = blockIdx.z;
    int count = counts[e];
    if (count > CAP) count = CAP;
    const int mrow0 = blockIdx.y * 128;
    if (mrow0 >= count) return;
    const int ncol0 = blockIdx.x * 128;
    const int tid = threadIdx.x;
    const int lane = tid & 63, wid = tid >> 6;
    const int wm = wid >> 1, wn = wid & 1;
    const int lrow = lane & 15, g4 = lane >> 4;

    __shared__ ushort As[128 * LDSK];
    __shared__ ushort Bs[128 * LDSK];

    // A staging (bf16): 2 units/thread: row = i*64 + (tid>>2), 8 k's at k8
    const int k8 = (tid & 3) * 8;
    bool aval[2];
    const ushort* haptr[2];
    int arow[2];
#pragma unroll
    for (int i = 0; i < 2; ++i) {
        int r = i * 64 + (tid >> 2);
        arow[i] = r;
        int rg = mrow0 + r;
        aval[i] = rg < count;
        haptr[i] = hbuf + (size_t)(e * CAP + (rg < CAP ? rg : 0)) * HH + k8;
    }
    // B staging: unit: 4 d-cols x 4 k-rows
    const int d0 = (tid & 31) * 4;
    const int k0 = (tid >> 5) * 4;
    const float* bptr = wd + ((size_t)e * HH + k0) * DD + ncol0 + d0;

    const f4v fz = {0.f, 0.f, 0.f, 0.f};
    const bf16x8 bz = {0, 0, 0, 0, 0, 0, 0, 0};
    bf16x8 areg[2];
    f4v breg[4];
    areg[0] = bz; areg[1] = bz;
#pragma unroll
    for (int j = 0; j < 4; ++j) breg[j] = fz;
    // prologue: load tile 0
#pragma unroll
    for (int i = 0; i < 2; ++i)
        if (aval[i]) areg[i] = *(const bf16x8*)(haptr[i]);
#pragma unroll
    for (int j = 0; j < 4; ++j) breg[j] = *(const f4v*)(bptr + (size_t)j * DD);

    f4v acc[4][4];
#pragma unroll
    for (int m = 0; m < 4; ++m)
#pragma unroll
        for (int n = 0; n < 4; ++n) acc[m][n] = fz;

    for (int kt = 0; kt < HH / BK; ++kt) {
#pragma unroll
        for (int i = 0; i < 2; ++i)
            *(bf16x8*)&As[arow[i] * LDSK + k8] = areg[i];
#pragma unroll
        for (int i = 0; i < 4; ++i) {
            bf16x4 col = {f2bf(breg[0][i]), f2bf(breg[1][i]), f2bf(breg[2][i]), f2bf(breg[3][i])};
            *(bf16x4*)&Bs[(d0 + i) * LDSK + k0] = col;
        }
        __syncthreads();
        if (kt < HH / BK - 1) {
            const int ko = (kt + 1) * BK;
#pragma unroll
            for (int i = 0; i < 2; ++i) {
                areg[i] = bz;
                if (aval[i]) areg[i] = *(const bf16x8*)(haptr[i] + ko);
            }
#pragma unroll
            for (int j = 0; j < 4; ++j)
                breg[j] = *(const f4v*)(bptr + ((size_t)ko + j) * DD);
        }
        bf16x8 af[4];
#pragma unroll
        for (int m = 0; m < 4; ++m) {
            const ushort* pa = &As[(wm * 64 + m * 16 + lrow) * LDSK + g4 * 4];
            union { bf16x8 v8; bf16x4 v4[2]; } u;
            u.v4[0] = *(const bf16x4*)pa;
            u.v4[1] = *(const bf16x4*)(pa + 16);
            af[m] = u.v8;
        }
#pragma unroll
        for (int n = 0; n < 4; ++n) {
            const int c = (wn * 64 + n * 16 + lrow) * LDSK + g4 * 4;
            union { bf16x8 v8; bf16x4 v4[2]; } ub;
            ub.v4[0] = *(const bf16x4*)&Bs[c];
            ub.v4[1] = *(const bf16x4*)&Bs[c + 16];
#pragma unroll
            for (int m = 0; m < 4; ++m)
                acc[m][n] = __builtin_amdgcn_mfma_f32_16x16x32_bf16(af[m], ub.v8, acc[m][n], 0, 0, 0);
        }
        __syncthreads();
    }

#pragma unroll
    for (int m = 0; m < 4; ++m) {
#pragma unroll
        for (int r = 0; r < 4; ++r) {
            int row = mrow0 + wm * 64 + m * 16 + g4 * 4 + r;
            if (row < count) {
                int tok = slot_token[e * CAP + row];
                float* obase = out + (size_t)tok * DD + ncol0 + wn * 64;
#pragma unroll
                for (int n = 0; n < 4; ++n) atomicAdd(obase + n * 16 + lrow, acc[m][n][r]);
            }
        }
    }
}

extern "C" void kernel_launch(void* const* d_in, const int* in_sizes, int n_in,
                              void* d_out, int out_size, void* d_ws, size_t ws_size,
                              hipStream_t stream) {
    const float* x = (const float*)d_in[0];       // [1,2048,2048]
    const float* gw = (const float*)d_in[1];      // [2048,64]
    const float* wg = (const float*)d_in[2];      // [64,2048,1024]
    const float* wu = (const float*)d_in[3];      // [64,2048,1024]
    const float* wd = (const float*)d_in[4];      // [64,1024,2048]
    float* out = (float*)d_out;                   // [T*D] then logits [T*E]
    float* logits = out + (size_t)TT * DD;

    char* ws = (char*)d_ws;
    int* counts = (int*)ws;                                      // 256 B
    int* slot_token = (int*)(ws + 1024);                         // 128 KB
    float* slot_wt = (float*)(ws + 1024 + NUM_E * CAP * 4);      // 128 KB
    ushort* hbuf = (ushort*)(ws + 1024 + 2 * NUM_E * CAP * 4);   // 64 MB bf16 [E*CAP][H]

    k_init<<<1024, 256, 0, stream>>>(out, counts);
    k_router<<<TT / 16, 256, 0, stream>>>(x, gw, logits);
    k_topk<<<TT / 4, 256, 0, stream>>>(logits, counts, slot_token, slot_wt);
    k_gateup<<<dim3(HH / 64, CAP / 128, NUM_E), 256, 0, stream>>>(x, wg, wu, counts, slot_token, slot_wt, hbuf);
    k_down<<<dim3(DD / 128, CAP / 128, NUM_E), 256, 0, stream>>>(hbuf, wd, counts, slot_token, out);
}

// Round 3
// 854.566 us; speedup vs baseline: 2.3099x; 1.1759x over previous
//
#include <hip/hip_runtime.h>
#include <hip/hip_bf16.h>

#define NUM_E 64
#define KTOP 8
#define CAP 512
#define TT 2048
#define DD 2048
#define HH 1024

#define BK 32
#define LDSK 36  // 72B rows: 18 banks/row, gcd(18,32)=2 -> all b64 access classes at the
                 // 4-lane/bank minimum (vs 8-way with 80B rows). 8B-aligned granules.

typedef __attribute__((ext_vector_type(4))) float f4v;
typedef __attribute__((ext_vector_type(8))) short bf16x8;
typedef __attribute__((ext_vector_type(4))) short bf16x4;

static __device__ __forceinline__ short f2bf(float f) {
    __bf16 b = (__bf16)f;
    return __builtin_bit_cast(short, b);
}

// ---------------- init: zero out[] and counts[] ----------------
__global__ __launch_bounds__(256) void k_init(float* __restrict__ out, int* __restrict__ counts) {
    int idx = blockIdx.x * 256 + threadIdx.x;
    f4v z = {0.f, 0.f, 0.f, 0.f};
    f4v* o4 = (f4v*)out;
    for (int i = idx; i < (TT * DD) / 4; i += 1024 * 256) o4[i] = z;
    if (idx < NUM_E) counts[idx] = 0;
}

// ---------------- router: logits = x @ gate_w (f32) ----------------
// 8 tokens/block staged in LDS; wave w computes 2 tokens, lane = expert.
#define RTOK 8
__global__ __launch_bounds__(256) void k_router(const float* __restrict__ x,
                                                const float* __restrict__ gw,
                                                float* __restrict__ logits) {
    __shared__ float xs[RTOK][512];
    const int tid = threadIdx.x;
    const int lane = tid & 63, wid = tid >> 6;
    const int t0 = blockIdx.x * RTOK;
    float a0 = 0.f, a1 = 0.f;
    for (int c = 0; c < DD / 512; ++c) {
        __syncthreads();
#pragma unroll
        for (int u = tid * 4; u < RTOK * 512; u += 1024) {
            int r = u >> 9, col = u & 511;
            *(f4v*)&xs[r][col] = *(const f4v*)&x[(size_t)(t0 + r) * DD + c * 512 + col];
        }
        __syncthreads();
        const float* gcol = gw + (size_t)c * 512 * NUM_E + lane;
#pragma unroll 8
        for (int d = 0; d < 512; ++d) {
            float g = gcol[(size_t)d * NUM_E];
            a0 = fmaf(xs[wid * 2 + 0][d], g, a0);
            a1 = fmaf(xs[wid * 2 + 1][d], g, a1);
        }
    }
    logits[(size_t)(t0 + wid * 2 + 0) * NUM_E + lane] = a0;
    logits[(size_t)(t0 + wid * 2 + 1) * NUM_E + lane] = a1;
}

// ---------------- topk + dispatch ----------------
__global__ __launch_bounds__(256) void k_topk(const float* __restrict__ logits,
                                              int* __restrict__ counts,
                                              int* __restrict__ slot_token,
                                              float* __restrict__ slot_wt) {
    int lane = threadIdx.x & 63, wid = threadIdx.x >> 6;
    int t = blockIdx.x * 4 + wid;
    float l = logits[(size_t)t * NUM_E + lane];
    float m = l;
#pragma unroll
    for (int off = 32; off; off >>= 1) m = fmaxf(m, __shfl_xor(m, off));
    float ex = __expf(l - m);
    float s = ex;
#pragma unroll
    for (int off = 32; off; off >>= 1) s += __shfl_xor(s, off);
    float p = ex / s;
#pragma unroll
    for (int k = 0; k < KTOP; ++k) {
        float v = p;
        int i = lane;
#pragma unroll
        for (int off = 32; off; off >>= 1) {
            float v2 = __shfl_xor(v, off);
            int i2 = __shfl_xor(i, off);
            if (v2 > v || (v2 == v && i2 < i)) { v = v2; i = i2; }
        }
        if (lane == i) {
            int pos = atomicAdd(&counts[i], 1);
            if (pos < CAP) {
                int slot = i * CAP + pos;
                slot_token[slot] = t;
                slot_wt[slot] = v;
            }
            p = -1.0f;
        }
    }
}

// ---------------- gate+up fused GEMM + SwiGLU -> h ----------------
// Block tile 128 rows x 64 h-cols. 4 waves (2x2); wave owns 64x32 with BOTH
// gate and up accumulators. Register prefetch of tile k+1 under MFMA of k.
__global__ __launch_bounds__(256, 3) void k_gateup(
    const float* __restrict__ x, const float* __restrict__ wg, const float* __restrict__ wu,
    const int* __restrict__ counts, const int* __restrict__ slot_token,
    const float* __restrict__ slot_wt, ushort* __restrict__ hbuf) {
    const int e = blockIdx.z;
    int count = counts[e];
    if (count > CAP) count = CAP;
    const int mrow0 = blockIdx.y * 128;
    if (mrow0 >= count) return;
    const int ncol0 = blockIdx.x * 64;
    const int tid = threadIdx.x;
    const int lane = tid & 63, wid = tid >> 6;
    const int wm = wid >> 1, wn = wid & 1;
    const int lrow = lane & 15, g4 = lane >> 4;

    __shared__ ushort As[128 * LDSK];
    __shared__ ushort Bgs[64 * LDSK];
    __shared__ ushort Bus[64 * LDSK];

    // A staging: 4 units/thread: row = i*32 + (tid>>3), 4 k's at ak
    const int ak = (tid & 7) * 4;
    const float* aptr[4];
    int arow[4];
#pragma unroll
    for (int i = 0; i < 4; ++i) {
        int r = i * 32 + (tid >> 3);
        arow[i] = r;
        int rg = mrow0 + r;
        if (rg < count) {
            int tok = slot_token[e * CAP + rg];
            aptr[i] = x + (size_t)tok * DD + ak;
        } else {
            aptr[i] = nullptr;
        }
    }

    // B staging: threads 0-127 -> Wg, 128-255 -> Wu. unit: 4 h-cols x 4 k-rows.
    const int bu_idx = tid & 127;
    const int bh = (bu_idx & 15) * 4;
    const int bk = (bu_idx >> 4) * 4;
    const float* bptr = ((tid < 128) ? wg : wu) + ((size_t)e * DD + bk) * HH + ncol0 + bh;
    ushort* bl = (tid < 128) ? Bgs : Bus;

    const f4v fz = {0.f, 0.f, 0.f, 0.f};
    f4v areg[4], breg[4];
#pragma unroll
    for (int i = 0; i < 4; ++i) { areg[i] = fz; breg[i] = fz; }
#pragma unroll
    for (int i = 0; i < 4; ++i)
        if (aptr[i]) areg[i] = *(const f4v*)(aptr[i]);
#pragma unroll
    for (int j = 0; j < 4; ++j) breg[j] = *(const f4v*)(bptr + (size_t)j * HH);

    f4v accg[4][2], accu[4][2];
#pragma unroll
    for (int m = 0; m < 4; ++m)
#pragma unroll
        for (int n = 0; n < 2; ++n) { accg[m][n] = fz; accu[m][n] = fz; }

    for (int kt = 0; kt < DD / BK; ++kt) {
#pragma unroll
        for (int i = 0; i < 4; ++i) {
            bf16x4 pk = {f2bf(areg[i][0]), f2bf(areg[i][1]), f2bf(areg[i][2]), f2bf(areg[i][3])};
            *(bf16x4*)&As[arow[i] * LDSK + ak] = pk;
        }
#pragma unroll
        for (int i = 0; i < 4; ++i) {
            bf16x4 col = {f2bf(breg[0][i]), f2bf(breg[1][i]), f2bf(breg[2][i]), f2bf(breg[3][i])};
            *(bf16x4*)&bl[(bh + i) * LDSK + bk] = col;
        }
        __syncthreads();
        if (kt < DD / BK - 1) {
            const int ko = (kt + 1) * BK;
#pragma unroll
            for (int i = 0; i < 4; ++i)
                if (aptr[i]) areg[i] = *(const f4v*)(aptr[i] + ko);
#pragma unroll
            for (int j = 0; j < 4; ++j)
                breg[j] = *(const f4v*)(bptr + ((size_t)ko + j) * HH);
        }
        bf16x8 af[4];
#pragma unroll
        for (int m = 0; m < 4; ++m) {
            const ushort* pa = &As[(wm * 64 + m * 16 + lrow) * LDSK + g4 * 4];
            union { bf16x8 v8; bf16x4 v4[2]; } u;
            u.v4[0] = *(const bf16x4*)pa;
            u.v4[1] = *(const bf16x4*)(pa + 16);
            af[m] = u.v8;
        }
#pragma unroll
        for (int n = 0; n < 2; ++n) {
            const int c = (wn * 32 + n * 16 + lrow) * LDSK + g4 * 4;
            union { bf16x8 v8; bf16x4 v4[2]; } ug, uu;
            ug.v4[0] = *(const bf16x4*)&Bgs[c];
            ug.v4[1] = *(const bf16x4*)&Bgs[c + 16];
            uu.v4[0] = *(const bf16x4*)&Bus[c];
            uu.v4[1] = *(const bf16x4*)&Bus[c + 16];
#pragma unroll
            for (int m = 0; m < 4; ++m) {
                accg[m][n] = __builtin_amdgcn_mfma_f32_16x16x32_bf16(af[m], ug.v8, accg[m][n], 0, 0, 0);
                accu[m][n] = __builtin_amdgcn_mfma_f32_16x16x32_bf16(af[m], uu.v8, accu[m][n], 0, 0, 0);
            }
        }
        __syncthreads();
    }

#pragma unroll
    for (int m = 0; m < 4; ++m) {
#pragma unroll
        for (int r = 0; r < 4; ++r) {
            int row = mrow0 + wm * 64 + m * 16 + g4 * 4 + r;
            if (row < count) {
                float wgt = slot_wt[e * CAP + row];
                size_t base = (size_t)(e * CAP + row) * HH + ncol0 + wn * 32;
#pragma unroll
                for (int n = 0; n < 2; ++n) {
                    float g = accg[m][n][r], uv = accu[m][n][r];
                    float hv = (g / (1.f + __expf(-g))) * uv * wgt;
                    hbuf[base + n * 16 + lrow] = (ushort)f2bf(hv);
                }
            }
        }
    }
}

// ---------------- down GEMM + scatter-add into out ----------------
// Block tile 128x128, 4 waves 2x2, wave 64x64. Register prefetch.
__global__ __launch_bounds__(256, 3) void k_down(
    const ushort* __restrict__ hbuf, const float* __restrict__ wd,
    const int* __restrict__ counts, const int* __restrict__ slot_token,
    float* __restrict__ out) {
    const int e = blockIdx.z;
    int count = counts[e];
    if (count > CAP) count = CAP;
    const int mrow0 = blockIdx.y * 128;
    if (mrow0 >= count) return;
    const int ncol0 = blockIdx.x * 128;
    const int tid = threadIdx.x;
    const int lane = tid & 63, wid = tid >> 6;
    const int wm = wid >> 1, wn = wid & 1;
    const int lrow = lane & 15, g4 = lane >> 4;

    __shared__ ushort As[128 * LDSK];
    __shared__ ushort Bs[128 * LDSK];

    // A staging (bf16): 2 units/thread: row = i*64 + (tid>>2), 16 k-bytes at k8
    const int k8 = (tid & 3) * 8;
    bool aval[2];
    const ushort* haptr[2];
    int arow[2];
#pragma unroll
    for (int i = 0; i < 2; ++i) {
        int r = i * 64 + (tid >> 2);
        arow[i] = r;
        int rg = mrow0 + r;
        aval[i] = rg < count;
        haptr[i] = hbuf + (size_t)(e * CAP + (rg < CAP ? rg : 0)) * HH + k8;
    }
    // B staging: unit 4 d-cols x 4 k-rows; thread map gives each wave 4 distinct
    // k-granules (bank-minimal writes) while 16 consecutive threads stay d-contiguous.
    const int dgrp = (tid & 15) | ((tid >> 7) << 4);   // 0..31
    const int kgrp = (tid >> 4) & 7;                   // 0..7
    const int d0 = dgrp * 4;
    const int k0 = kgrp * 4;
    const float* bptr = wd + ((size_t)e * HH + k0) * DD + ncol0 + d0;

    const f4v fz = {0.f, 0.f, 0.f, 0.f};
    const bf16x8 bz = {0, 0, 0, 0, 0, 0, 0, 0};
    bf16x8 areg[2];
    f4v breg[4];
    areg[0] = bz; areg[1] = bz;
#pragma unroll
    for (int j = 0; j < 4; ++j) breg[j] = fz;
#pragma unroll
    for (int i = 0; i < 2; ++i)
        if (aval[i]) areg[i] = *(const bf16x8*)(haptr[i]);
#pragma unroll
    for (int j = 0; j < 4; ++j) breg[j] = *(const f4v*)(bptr + (size_t)j * DD);

    f4v acc[4][4];
#pragma unroll
    for (int m = 0; m < 4; ++m)
#pragma unroll
        for (int n = 0; n < 4; ++n) acc[m][n] = fz;

    for (int kt = 0; kt < HH / BK; ++kt) {
#pragma unroll
        for (int i = 0; i < 2; ++i) {
            union { bf16x8 v8; bf16x4 v4[2]; } u;
            u.v8 = areg[i];
            *(bf16x4*)&As[arow[i] * LDSK + k8] = u.v4[0];
            *(bf16x4*)&As[arow[i] * LDSK + k8 + 4] = u.v4[1];
        }
#pragma unroll
        for (int i = 0; i < 4; ++i) {
            bf16x4 col = {f2bf(breg[0][i]), f2bf(breg[1][i]), f2bf(breg[2][i]), f2bf(breg[3][i])};
            *(bf16x4*)&Bs[(d0 + i) * LDSK + k0] = col;
        }
        __syncthreads();
        if (kt < HH / BK - 1) {
            const int ko = (kt + 1) * BK;
#pragma unroll
            for (int i = 0; i < 2; ++i) {
                areg[i] = bz;
                if (aval[i]) areg[i] = *(const bf16x8*)(haptr[i] + ko);
            }
#pragma unroll
            for (int j = 0; j < 4; ++j)
                breg[j] = *(const f4v*)(bptr + ((size_t)ko + j) * DD);
        }
        bf16x8 af[4];
#pragma unroll
        for (int m = 0; m < 4; ++m) {
            const ushort* pa = &As[(wm * 64 + m * 16 + lrow) * LDSK + g4 * 4];
            union { bf16x8 v8; bf16x4 v4[2]; } u;
            u.v4[0] = *(const bf16x4*)pa;
            u.v4[1] = *(const bf16x4*)(pa + 16);
            af[m] = u.v8;
        }
#pragma unroll
        for (int n = 0; n < 4; ++n) {
            const int c = (wn * 64 + n * 16 + lrow) * LDSK + g4 * 4;
            union { bf16x8 v8; bf16x4 v4[2]; } ub;
            ub.v4[0] = *(const bf16x4*)&Bs[c];
            ub.v4[1] = *(const bf16x4*)&Bs[c + 16];
#pragma unroll
            for (int m = 0; m < 4; ++m)
                acc[m][n] = __builtin_amdgcn_mfma_f32_16x16x32_bf16(af[m], ub.v8, acc[m][n], 0, 0, 0);
        }
        __syncthreads();
    }

#pragma unroll
    for (int m = 0; m < 4; ++m) {
#pragma unroll
        for (int r = 0; r < 4; ++r) {
            int row = mrow0 + wm * 64 + m * 16 + g4 * 4 + r;
            if (row < count) {
                int tok = slot_token[e * CAP + row];
                float* obase = out + (size_t)tok * DD + ncol0 + wn * 64;
#pragma unroll
                for (int n = 0; n < 4; ++n) atomicAdd(obase + n * 16 + lrow, acc[m][n][r]);
            }
        }
    }
}

extern "C" void kernel_launch(void* const* d_in, const int* in_sizes, int n_in,
                              void* d_out, int out_size, void* d_ws, size_t ws_size,
                              hipStream_t stream) {
    const float* x = (const float*)d_in[0];       // [1,2048,2048]
    const float* gw = (const float*)d_in[1];      // [2048,64]
    const float* wg = (const float*)d_in[2];      // [64,2048,1024]
    const float* wu = (const float*)d_in[3];      // [64,2048,1024]
    const float* wd = (const float*)d_in[4];      // [64,1024,2048]
    float* out = (float*)d_out;                   // [T*D] then logits [T*E]
    float* logits = out + (size_t)TT * DD;

    char* ws = (char*)d_ws;
    int* counts = (int*)ws;                                      // 256 B
    int* slot_token = (int*)(ws + 1024);                         // 128 KB
    float* slot_wt = (float*)(ws + 1024 + NUM_E * CAP * 4);      // 128 KB
    ushort* hbuf = (ushort*)(ws + 1024 + 2 * NUM_E * CAP * 4);   // 64 MB bf16 [E*CAP][H]

    k_init<<<1024, 256, 0, stream>>>(out, counts);
    k_router<<<TT / RTOK, 256, 0, stream>>>(x, gw, logits);
    k_topk<<<TT / 4, 256, 0, stream>>>(logits, counts, slot_token, slot_wt);
    k_gateup<<<dim3(HH / 64, CAP / 128, NUM_E), 256, 0, stream>>>(x, wg, wu, counts, slot_token, slot_wt, hbuf);
    k_down<<<dim3(DD / 128, CAP / 128, NUM_E), 256, 0, stream>>>(hbuf, wd, counts, slot_token, out);
}